// Round 1
// baseline (249.465 us; speedup 1.0000x reference)
//
#include <hip/hip_runtime.h>
#include <math.h>

#define NUM_GT   128
#define NUM_PROP 512
#define IMG_H    520
#define IMG_W    704
#define MS       28
#define LOGITS_N (NUM_PROP * 2 * MS * MS)   // 802816

// ws layout: [0]=bce_sum, [1]=npos, [2]=sqsum, then matched[512] (int), pos[512] (float)
#define WS_MATCHED_OFF 256
#define WS_POS_OFF     (256 + NUM_PROP * 4)
#define WS_ZERO_BYTES  (256 + NUM_PROP * 8)

// ---------------- kernel 1: IoU match ----------------
__global__ void match_kernel(const float* __restrict__ proposals,
                             const float* __restrict__ gt_boxes,
                             int* __restrict__ matched,
                             float* __restrict__ pos,
                             float* __restrict__ npos) {
    __shared__ float gb[NUM_GT * 4];
    for (int i = threadIdx.x; i < NUM_GT * 4; i += blockDim.x) gb[i] = gt_boxes[i];
    __syncthreads();

    int p = blockIdx.x * blockDim.x + threadIdx.x;
    if (p >= NUM_PROP) return;

    float ax1 = proposals[p * 4 + 0];
    float ay1 = proposals[p * 4 + 1];
    float ax2 = proposals[p * 4 + 2];
    float ay2 = proposals[p * 4 + 3];
    float area_a = (ax2 - ax1) * (ay2 - ay1);

    float best = -1e30f;
    int bi = 0;
    for (int g = 0; g < NUM_GT; ++g) {
        float bx1 = gb[g * 4 + 0];
        float by1 = gb[g * 4 + 1];
        float bx2 = gb[g * 4 + 2];
        float by2 = gb[g * 4 + 3];
        float area_b = (bx2 - bx1) * (by2 - by1);
        float ltx = fmaxf(ax1, bx1), lty = fmaxf(ay1, by1);
        float rbx = fminf(ax2, bx2), rby = fminf(ay2, by2);
        float w = fmaxf(rbx - ltx, 0.0f);
        float h = fmaxf(rby - lty, 0.0f);
        float inter = w * h;
        float iou = inter / (area_a + area_b - inter);
        if (iou > best) { best = iou; bi = g; }   // strict > => first-index tie-break (jnp.argmax)
    }
    matched[p] = bi;
    float ps = (best > 0.5f) ? 1.0f : 0.0f;
    pos[p] = ps;
    atomicAdd(npos, ps);
}

// ---------------- kernel 2: crop-resize + BCE (one block per proposal) ----------------
__global__ void bce_kernel(const float* __restrict__ gt_boxes,
                           const float* __restrict__ gt_masks,
                           const float* __restrict__ mask_logits,
                           const int* __restrict__ matched,
                           const float* __restrict__ pos,
                           float* __restrict__ bce_sum) {
    const int p = blockIdx.x;
    const int t = threadIdx.x;

    __shared__ int   s_gidx;
    __shared__ int   s_x0[MS], s_x1[MS], s_y0[MS], s_y1[MS];
    __shared__ float s_wx[MS], s_wy[MS];
    __shared__ float red[4];

    if (t == 0) s_gidx = matched[p];
    __syncthreads();
    const int g = s_gidx;

    // box of matched gt (all threads read the same 4 floats — broadcast)
    const float b0 = gt_boxes[g * 4 + 0];
    const float b1 = gt_boxes[g * 4 + 1];
    const float b2 = gt_boxes[g * 4 + 2];
    const float b3 = gt_boxes[g * 4 + 3];

    // int cast truncates toward zero, matching astype(int32)
    int x1 = min(max((int)b0, 0), IMG_W - 1);
    int y1 = min(max((int)b1, 0), IMG_H - 1);
    int x2 = max(x1 + 1, min((int)b2, IMG_W));
    int y2 = max(y1 + 1, min((int)b3, IMG_H));
    int cwi = x2 - x1;
    int chi = y2 - y1;
    float cw = (float)cwi;
    float ch = (float)chi;

    if (t < MS) {
        float j = (float)t + 0.5f;
        float sx = fminf(fmaxf(j * cw / 28.0f - 0.5f, 0.0f), cw - 1.0f);
        float x0f = floorf(sx);
        int x0i = (int)x0f;
        s_wx[t] = sx - x0f;
        s_x0[t] = x0i + x1;
        s_x1[t] = min(x0i + 1, cwi - 1) + x1;

        float sy = fminf(fmaxf(j * ch / 28.0f - 0.5f, 0.0f), ch - 1.0f);
        float y0f = floorf(sy);
        int y0i = (int)y0f;
        s_wy[t] = sy - y0f;
        s_y0[t] = y0i + y1;
        s_y1[t] = min(y0i + 1, chi - 1) + y1;
    }
    __syncthreads();

    const float* m  = gt_masks + (size_t)g * IMG_H * IMG_W;
    const float* lg = mask_logits + ((size_t)p * 2 + 1) * (MS * MS);

    float acc = 0.0f;
    for (int idx = t; idx < MS * MS; idx += blockDim.x) {
        int i = idx / MS;
        int j = idx - i * MS;
        float wx = s_wx[j], wy = s_wy[i];
        const float* r0 = m + (size_t)s_y0[i] * IMG_W;
        const float* r1 = m + (size_t)s_y1[i] * IMG_W;
        int cx0 = s_x0[j], cx1 = s_x1[j];
        float v00 = r0[cx0], v01 = r0[cx1];
        float v10 = r1[cx0], v11 = r1[cx1];
        float top = (1.0f - wx) * v00 + wx * v01;
        float bot = (1.0f - wx) * v10 + wx * v11;
        float tv  = (1.0f - wy) * top + wy * bot;
        float l = lg[idx];
        float bce = fmaxf(l, 0.0f) - l * tv + log1pf(expf(-fabsf(l)));
        acc += bce;
    }

    // block reduce (4 waves of 64)
    float v = acc;
    #pragma unroll
    for (int o = 32; o > 0; o >>= 1) v += __shfl_down(v, o, 64);
    int lane = t & 63, wid = t >> 6;
    if (lane == 0) red[wid] = v;
    __syncthreads();
    if (t == 0) {
        float s = red[0] + red[1] + red[2] + red[3];
        atomicAdd(bce_sum, s * pos[p]);
    }
}

// ---------------- kernel 3: sum(mask_logits^2) ----------------
__global__ void sq_kernel(const float* __restrict__ mask_logits,
                          float* __restrict__ sqsum) {
    const int nvec = LOGITS_N / 4;  // 200704
    const float4* src = (const float4*)mask_logits;
    float acc = 0.0f;
    for (int i = blockIdx.x * blockDim.x + threadIdx.x; i < nvec;
         i += gridDim.x * blockDim.x) {
        float4 x = src[i];
        acc += x.x * x.x + x.y * x.y + x.z * x.z + x.w * x.w;
    }
    float v = acc;
    #pragma unroll
    for (int o = 32; o > 0; o >>= 1) v += __shfl_down(v, o, 64);
    __shared__ float red[4];
    int lane = threadIdx.x & 63, wid = threadIdx.x >> 6;
    if (lane == 0) red[wid] = v;
    __syncthreads();
    if (threadIdx.x == 0) {
        float s = red[0] + red[1] + red[2] + red[3];
        atomicAdd(sqsum, s);
    }
}

// ---------------- kernel 4: finalize ----------------
__global__ void final_kernel(const float* __restrict__ acc, float* __restrict__ out) {
    float bce  = acc[0];
    float npos = acc[1];
    float sq   = acc[2];
    float loss_pos = bce / (fmaxf(npos, 1.0f) * (float)(MS * MS));
    float loss_neg = (sq / (float)LOGITS_N) * 0.01f;
    out[0] = (npos > 0.0f) ? loss_pos : loss_neg;
}

extern "C" void kernel_launch(void* const* d_in, const int* in_sizes, int n_in,
                              void* d_out, int out_size, void* d_ws, size_t ws_size,
                              hipStream_t stream) {
    const float* proposals   = (const float*)d_in[0];
    const float* gt_boxes    = (const float*)d_in[1];
    const float* gt_masks    = (const float*)d_in[2];
    const float* mask_logits = (const float*)d_in[3];
    float* out = (float*)d_out;

    float* acc     = (float*)d_ws;                              // [0]=bce,[1]=npos,[2]=sq
    int*   matched = (int*)((char*)d_ws + WS_MATCHED_OFF);
    float* pos     = (float*)((char*)d_ws + WS_POS_OFF);

    hipMemsetAsync(d_ws, 0, WS_ZERO_BYTES, stream);

    match_kernel<<<(NUM_PROP + 255) / 256, 256, 0, stream>>>(proposals, gt_boxes,
                                                             matched, pos, acc + 1);
    bce_kernel<<<NUM_PROP, 256, 0, stream>>>(gt_boxes, gt_masks, mask_logits,
                                             matched, pos, acc + 0);
    sq_kernel<<<128, 256, 0, stream>>>(mask_logits, acc + 2);
    final_kernel<<<1, 1, 0, stream>>>(acc, out);
}